// Round 3
// baseline (535.652 us; speedup 1.0000x reference)
//
#include <hip/hip_runtime.h>
#include <hip/hip_bf16.h>

typedef __attribute__((ext_vector_type(8))) short short8;
typedef __attribute__((ext_vector_type(4))) float f32x4;

#define MFMA16(a, b, c) __builtin_amdgcn_mfma_f32_16x16x32_bf16((a), (b), (c), 0, 0, 0)

__device__ __forceinline__ unsigned short f2bf(float x) {
    union { float f; unsigned int u; } v; v.f = x;
    unsigned int u = v.u;
    return (unsigned short)((u + 0x7FFFu + ((u >> 16) & 1u)) >> 16);
}

__device__ __forceinline__ short8 ld8(const unsigned short* p) {
    return *reinterpret_cast<const short8*>(p);
}

// ---- K0: bbn fp32 -> bf16, row sums s[i] (fp32) ------------------------------
__global__ void k_prep_bbn(const float* __restrict__ bbn, unsigned short* __restrict__ bbn_h,
                           float* __restrict__ s) {
    int row = blockIdx.x * 4 + (threadIdx.x >> 6);
    int lane = threadIdx.x & 63;
    float x = bbn[row * 64 + lane];
    bbn_h[row * 64 + lane] = f2bf(x);
    float v = x;
    #pragma unroll
    for (int m = 1; m < 64; m <<= 1) v += __shfl_xor(v, m);
    if (lane == 0) s[row] = v;
}

// ---- K0b/K2: transpose (+optional rsqrt(d) row scale), fp32 -> bf16 ----------
__global__ void k_transpose_scale(const float* __restrict__ in, unsigned short* __restrict__ out,
                                  const float* __restrict__ dvec, int K, int N) {
    __shared__ float tile[64][65];
    int tiles_k = K >> 6;
    int tk = blockIdx.x % tiles_k, tn = blockIdx.x / tiles_k;
    int k0 = tk * 64, n0 = tn * 64;
    int c = threadIdx.x & 63, rq = threadIdx.x >> 6;
    #pragma unroll
    for (int i = 0; i < 16; ++i) {
        int r = rq + 4 * i;
        float sc = dvec ? rsqrtf(dvec[k0 + r]) : 1.0f;
        tile[r][c] = in[(size_t)(k0 + r) * N + n0 + c] * sc;
    }
    __syncthreads();
    #pragma unroll
    for (int i = 0; i < 16; ++i) {
        int r = rq + 4 * i;
        out[(size_t)(n0 + r) * K + k0 + c] = f2bf(tile[c][r]);
    }
}

// ---- K1: degree d[i] = sum_j (1 - |2*G_ij - s_i - s_j|/64)^1.4 ---------------
// 512 blocks x 16 rows, 8 waves each over j-subtiles (2 blocks/CU)
__global__ __launch_bounds__(512) void k_degree(const unsigned short* __restrict__ bbn_h,
                                                const float* __restrict__ s,
                                                float* __restrict__ d) {
    int i0 = blockIdx.x * 16;
    int tid = threadIdx.x;
    int w = tid >> 6, l = tid & 63, g = l >> 4, c = l & 15;

    const unsigned short* ap = bbn_h + (i0 + c) * 64;
    short8 a0 = ld8(ap);
    short8 a1 = ld8(ap + 32);
    f32x4 si4 = *reinterpret_cast<const f32x4*>(s + i0 + g * 4);

    float acc[4] = {0.f, 0.f, 0.f, 0.f};
    #pragma unroll 2
    for (int j0 = w * 16; j0 < 8192; j0 += 128) {
        int jrow = j0 + c;
        const unsigned short* bp = bbn_h + jrow * 64;
        short8 b0 = ld8(bp);
        short8 b1 = ld8(bp + 32);
        float sj = s[jrow];
        f32x4 gf = {0.f, 0.f, 0.f, 0.f};
        gf = MFMA16(a0, b0, gf);
        gf = MFMA16(a1, b1, gf);
        #pragma unroll
        for (int r = 0; r < 4; ++r) {
            float t = fmaf(2.f, gf[r], -(si4[r] + sj));
            float x = fmaf(fabsf(t), -0.015625f, 1.f);
            x = fmaxf(x, 0.f);
            acc[r] += exp2f(1.4f * log2f(x));
        }
    }

    __shared__ float part[8][16];
    #pragma unroll
    for (int r = 0; r < 4; ++r) {
        float v = acc[r];
        v += __shfl_xor(v, 1); v += __shfl_xor(v, 2);
        v += __shfl_xor(v, 4); v += __shfl_xor(v, 8);
        if (c == 0) part[w][g * 4 + r] = v;
    }
    __syncthreads();
    if (tid < 16) {
        float v = 0.f;
        #pragma unroll
        for (int ww = 0; ww < 8; ++ww) v += part[ww][tid];
        d[i0 + tid] = v;
    }
}

// ---- K3: fused h = D^-1/2 A D^-1/2 cbn ---------------------------------------
// BM=64, BN=256, BK=64; 1024 threads (16 waves). Main: 2x8 wave grid, 32x32/wave.
// Gen: 16 waves x one 16x16 subtile, swapped MFMA -> packed ds_write_b64.
// Double-buffered A-LDS, ONE barrier per j-iteration.
__global__ __launch_bounds__(1024, 4) void k_spectral(const unsigned short* __restrict__ bbn_h,
                                                      const float* __restrict__ s,
                                                      const float* __restrict__ d,
                                                      const unsigned short* __restrict__ cbn_sT,
                                                      unsigned short* __restrict__ h) {
    int bx = blockIdx.x;
    int xcd = bx & 7, hi = bx >> 3;
    int i0 = (hi * 4 + (xcd & 3)) * 64;
    int n0 = (xcd >> 2) * 256;

    int tid = threadIdx.x;
    int w = tid >> 6, l = tid & 63, g = l >> 4, c = l & 15;
    int wm = w >> 3, wn = w & 7;      // main wave tile: rows wm*32, cols wn*32
    int gi = w & 3, gj = w >> 2;      // gen subtile: i-rows gi*16, j-rows gj*16

    const unsigned short* arow_p = bbn_h + (i0 + gi * 16 + c) * 64;
    short8 ga0 = ld8(arow_p);
    short8 ga1 = ld8(arow_p + 32);
    float si = s[i0 + gi * 16 + c];

    __shared__ unsigned char Alds[2][64 * 128];

    f32x4 acc[2][2] = {};

    // prologue: gen tile 0 into buf 0
    {
        const unsigned short* brow_p = bbn_h + (gj * 16 + c) * 64;
        short8 b0 = ld8(brow_p);
        short8 b1 = ld8(brow_p + 32);
        f32x4 sj4 = *reinterpret_cast<const f32x4*>(s + gj * 16 + g * 4);
        f32x4 gf = {0.f, 0.f, 0.f, 0.f};
        gf = MFMA16(b0, ga0, gf);   // swapped: D[j][i]
        gf = MFMA16(b1, ga1, gf);
        unsigned int u01, u23;
        {
            unsigned short u[4];
            #pragma unroll
            for (int r = 0; r < 4; ++r) {
                float t = fmaf(2.f, gf[r], -(si + sj4[r]));
                float x = fmaf(fabsf(t), -0.015625f, 1.f);
                x = fmaxf(x, 0.f);
                u[r] = f2bf(exp2f(1.4f * log2f(x)));
            }
            u01 = (unsigned int)u[0] | ((unsigned int)u[1] << 16);
            u23 = (unsigned int)u[2] | ((unsigned int)u[3] << 16);
        }
        int row = gi * 16 + c;
        int bo = (row * 128 + (gj * 16 + g * 4) * 2) ^ ((c & 7) << 4);
        *reinterpret_cast<uint2*>(Alds[0] + bo) = make_uint2(u01, u23);
    }
    __syncthreads();

    for (int t = 0; t < 128; ++t) {
        int j0 = t << 6;
        int cur = t & 1;
        bool do_gen = (t + 1 < 128);

        // gen loads for tile t+1 (issue first: longest latency)
        short8 b0, b1; f32x4 sj4;
        if (do_gen) {
            int jn = j0 + 64;
            const unsigned short* brow_p = bbn_h + (jn + gj * 16 + c) * 64;
            b0 = ld8(brow_p);
            b1 = ld8(brow_p + 32);
            sj4 = *reinterpret_cast<const f32x4*>(s + jn + gj * 16 + g * 4);
        }

        // B fragments for tile t (L2-resident cbn_sT)
        short8 bfr[2][2];
        #pragma unroll
        for (int kk = 0; kk < 2; ++kk)
            #pragma unroll
            for (int nn = 0; nn < 2; ++nn)
                bfr[kk][nn] = ld8(cbn_sT + (size_t)(n0 + wn * 32 + nn * 16 + c) * 8192 + j0 + kk * 32 + g * 8);

        // A fragments for tile t from Alds[cur]
        short8 af[2][2];
        #pragma unroll
        for (int mi = 0; mi < 2; ++mi)
            #pragma unroll
            for (int kk = 0; kk < 2; ++kk) {
                int row = wm * 32 + mi * 16 + c;
                int bo = (row * 128 + kk * 64 + g * 16) ^ ((c & 7) << 4);
                af[mi][kk] = *reinterpret_cast<const short8*>(Alds[cur] + bo);
            }

        // gen compute tile t+1 into Alds[cur^1]
        if (do_gen) {
            f32x4 gf = {0.f, 0.f, 0.f, 0.f};
            gf = MFMA16(b0, ga0, gf);
            gf = MFMA16(b1, ga1, gf);
            unsigned short u[4];
            #pragma unroll
            for (int r = 0; r < 4; ++r) {
                float t2 = fmaf(2.f, gf[r], -(si + sj4[r]));
                float x = fmaf(fabsf(t2), -0.015625f, 1.f);
                x = fmaxf(x, 0.f);
                u[r] = f2bf(exp2f(1.4f * log2f(x)));
            }
            unsigned int u01 = (unsigned int)u[0] | ((unsigned int)u[1] << 16);
            unsigned int u23 = (unsigned int)u[2] | ((unsigned int)u[3] << 16);
            int row = gi * 16 + c;
            int bo = (row * 128 + (gj * 16 + g * 4) * 2) ^ ((c & 7) << 4);
            *reinterpret_cast<uint2*>(Alds[cur ^ 1] + bo) = make_uint2(u01, u23);
        }

        // main MFMAs for tile t
        #pragma unroll
        for (int kk = 0; kk < 2; ++kk)
            #pragma unroll
            for (int nn = 0; nn < 2; ++nn) {
                acc[0][nn] = MFMA16(af[0][kk], bfr[kk][nn], acc[0][nn]);
                acc[1][nn] = MFMA16(af[1][kk], bfr[kk][nn], acc[1][nn]);
            }

        __syncthreads();
    }

    // epilogue: scale by dinv_i, store bf16 h
    #pragma unroll
    for (int mi = 0; mi < 2; ++mi) {
        f32x4 d4 = *reinterpret_cast<const f32x4*>(d + i0 + wm * 32 + mi * 16 + g * 4);
        #pragma unroll
        for (int r = 0; r < 4; ++r) {
            int row = i0 + wm * 32 + mi * 16 + g * 4 + r;
            float dinv = rsqrtf(d4[r]);
            #pragma unroll
            for (int nn = 0; nn < 2; ++nn)
                h[(size_t)row * 512 + n0 + wn * 32 + nn * 16 + c] = f2bf(acc[mi][nn][r] * dinv);
        }
    }
}

// ---- K4: out = sigmoid(h @ W + b), fp32 out ----------------------------------
// 512 blocks: 256 row-tiles (32 rows) x 2 col-tiles (256 cols); 8 waves 2x4
__global__ __launch_bounds__(512) void k_out(const unsigned short* __restrict__ h,
                                             const unsigned short* __restrict__ Wt,
                                             const float* __restrict__ b,
                                             float* __restrict__ out) {
    int bx = blockIdx.x;
    int i0 = (bx & 255) * 32, n0 = (bx >> 8) * 256;
    int tid = threadIdx.x;
    int w = tid >> 6, l = tid & 63, g = l >> 4, c = l & 15;
    int wm = w >> 2, wn = w & 3;   // rows wm*16, cols wn*64

    float bb[4];
    #pragma unroll
    for (int nn = 0; nn < 4; ++nn) bb[nn] = b[n0 + wn * 64 + nn * 16 + c];

    f32x4 acc[4] = {};
    for (int k0 = 0; k0 < 512; k0 += 64) {
        short8 af[2];
        #pragma unroll
        for (int kk = 0; kk < 2; ++kk)
            af[kk] = ld8(h + (size_t)(i0 + wm * 16 + c) * 512 + k0 + kk * 32 + g * 8);
        #pragma unroll
        for (int kk = 0; kk < 2; ++kk)
            #pragma unroll
            for (int nn = 0; nn < 4; ++nn) {
                short8 bf = ld8(Wt + (size_t)(n0 + wn * 64 + nn * 16 + c) * 512 + k0 + kk * 32 + g * 8);
                acc[nn] = MFMA16(af[kk], bf, acc[nn]);
            }
    }
    #pragma unroll
    for (int r = 0; r < 4; ++r) {
        int row = i0 + wm * 16 + g * 4 + r;
        #pragma unroll
        for (int nn = 0; nn < 4; ++nn) {
            float z = acc[nn][r] + bb[nn];
            out[(size_t)row * 512 + n0 + wn * 64 + nn * 16 + c] = 1.f / (1.f + exp2f(-1.44269504f * z));
        }
    }
}

extern "C" void kernel_launch(void* const* d_in, const int* in_sizes, int n_in,
                              void* d_out, int out_size, void* d_ws, size_t ws_size,
                              hipStream_t stream) {
    const float* bbn = (const float*)d_in[0];   // [8192, 64]
    const float* cbn = (const float*)d_in[1];   // [8192, 512]
    const float* W   = (const float*)d_in[2];   // [512, 512]
    const float* b   = (const float*)d_in[3];   // [512]
    float* out = (float*)d_out;                 // [8192, 512] fp32

    char* ws = (char*)d_ws;
    unsigned short* bbn_h  = (unsigned short*)(ws);                    // 1 MB
    float*          s      = (float*)(ws + (1u << 20));                // 32 KB
    float*          dd     = (float*)(ws + (1u << 20) + (1u << 15));   // 32 KB
    unsigned short* Wt     = (unsigned short*)(ws + (1u << 20) + (2u << 15));           // 512 KB
    unsigned short* cbn_sT = (unsigned short*)(ws + (1u << 20) + (2u << 15) + (1u << 19));        // 8 MB
    unsigned short* hbuf   = (unsigned short*)(ws + (1u << 20) + (2u << 15) + (1u << 19) + (1u << 23)); // 8 MB

    k_prep_bbn<<<2048, 256, 0, stream>>>(bbn, bbn_h, s);
    k_transpose_scale<<<64, 256, 0, stream>>>(W, Wt, nullptr, 512, 512);
    k_degree<<<512, 512, 0, stream>>>(bbn_h, s, dd);
    k_transpose_scale<<<1024, 256, 0, stream>>>(cbn, cbn_sT, dd, 8192, 512);
    k_spectral<<<256, 1024, 0, stream>>>(bbn_h, s, dd, cbn_sT, hbuf);
    k_out<<<512, 512, 0, stream>>>(hbuf, Wt, b, out);
}

// Round 4
// 487.009 us; speedup vs baseline: 1.0999x; 1.0999x over previous
//
#include <hip/hip_runtime.h>
#include <hip/hip_bf16.h>

typedef __attribute__((ext_vector_type(8))) short short8;
typedef __attribute__((ext_vector_type(4))) float f32x4;

#define MFMA16(a, b, c) __builtin_amdgcn_mfma_f32_16x16x32_bf16((a), (b), (c), 0, 0, 0)

__device__ __forceinline__ unsigned short f2bf(float x) {
    union { float f; unsigned int u; } v; v.f = x;
    unsigned int u = v.u;
    return (unsigned short)((u + 0x7FFFu + ((u >> 16) & 1u)) >> 16);
}

__device__ __forceinline__ short8 ld8(const unsigned short* p) {
    return *reinterpret_cast<const short8*>(p);
}

// ---- K0: bbn fp32 -> bf16, row sums s[i] (fp32) ------------------------------
__global__ void k_prep_bbn(const float* __restrict__ bbn, unsigned short* __restrict__ bbn_h,
                           float* __restrict__ s) {
    int row = blockIdx.x * 4 + (threadIdx.x >> 6);
    int lane = threadIdx.x & 63;
    float x = bbn[row * 64 + lane];
    bbn_h[row * 64 + lane] = f2bf(x);
    float v = x;
    #pragma unroll
    for (int m = 1; m < 64; m <<= 1) v += __shfl_xor(v, m);
    if (lane == 0) s[row] = v;
}

// ---- K0b/K2: transpose (+optional rsqrt(d) row scale), fp32 -> bf16 ----------
__global__ void k_transpose_scale(const float* __restrict__ in, unsigned short* __restrict__ out,
                                  const float* __restrict__ dvec, int K, int N) {
    __shared__ float tile[64][65];
    int tiles_k = K >> 6;
    int tk = blockIdx.x % tiles_k, tn = blockIdx.x / tiles_k;
    int k0 = tk * 64, n0 = tn * 64;
    int c = threadIdx.x & 63, rq = threadIdx.x >> 6;
    #pragma unroll
    for (int i = 0; i < 16; ++i) {
        int r = rq + 4 * i;
        float sc = dvec ? rsqrtf(dvec[k0 + r]) : 1.0f;
        tile[r][c] = in[(size_t)(k0 + r) * N + n0 + c] * sc;
    }
    __syncthreads();
    #pragma unroll
    for (int i = 0; i < 16; ++i) {
        int r = rq + 4 * i;
        out[(size_t)(n0 + r) * K + k0 + c] = f2bf(tile[c][r]);
    }
}

// ---- K1: degree d[i] = sum_j (1 - |2*G_ij - s_i - s_j|/64)^1.4 ---------------
__global__ __launch_bounds__(512) void k_degree(const unsigned short* __restrict__ bbn_h,
                                                const float* __restrict__ s,
                                                float* __restrict__ d) {
    int i0 = blockIdx.x * 16;
    int tid = threadIdx.x;
    int w = tid >> 6, l = tid & 63, g = l >> 4, c = l & 15;

    const unsigned short* ap = bbn_h + (i0 + c) * 64;
    short8 a0 = ld8(ap);
    short8 a1 = ld8(ap + 32);
    f32x4 si4 = *reinterpret_cast<const f32x4*>(s + i0 + g * 4);

    float acc[4] = {0.f, 0.f, 0.f, 0.f};
    #pragma unroll 4
    for (int j0 = w * 16; j0 < 8192; j0 += 128) {
        int jrow = j0 + c;
        const unsigned short* bp = bbn_h + jrow * 64;
        short8 b0 = ld8(bp);
        short8 b1 = ld8(bp + 32);
        float sj = s[jrow];
        f32x4 gf = {0.f, 0.f, 0.f, 0.f};
        gf = MFMA16(a0, b0, gf);
        gf = MFMA16(a1, b1, gf);
        #pragma unroll
        for (int r = 0; r < 4; ++r) {
            float t = fmaf(2.f, gf[r], -(si4[r] + sj));
            float x = fmaf(fabsf(t), -0.015625f, 1.f);
            x = fmaxf(x, 0.f);
            acc[r] += exp2f(1.4f * log2f(x));
        }
    }

    __shared__ float part[8][16];
    #pragma unroll
    for (int r = 0; r < 4; ++r) {
        float v = acc[r];
        v += __shfl_xor(v, 1); v += __shfl_xor(v, 2);
        v += __shfl_xor(v, 4); v += __shfl_xor(v, 8);
        if (c == 0) part[w][g * 4 + r] = v;
    }
    __syncthreads();
    if (tid < 16) {
        float v = 0.f;
        #pragma unroll
        for (int ww = 0; ww < 8; ++ww) v += part[ww][tid];
        d[i0 + tid] = v;
    }
}

// ---- K3: fused h = D^-1/2 A D^-1/2 cbn ---------------------------------------
// BM=64, BN=256, BK=64; 1024 threads (16 waves). Main: 2x8 waves, 32x32/wave.
// Gen: 16 waves x one 16x16 subtile, swapped MFMA -> packed ds_write_b64.
// Register pipeline: gen loads for tile t+2 issued at iter t, consumed iter t+1;
// gen compute sits between bfr issue and main MFMAs to cover B-frag L2 latency.
// ONE barrier per iteration; LDS A double-buffered.
__global__ __launch_bounds__(1024, 4) void k_spectral(const unsigned short* __restrict__ bbn_h,
                                                      const float* __restrict__ s,
                                                      const float* __restrict__ d,
                                                      const unsigned short* __restrict__ cbn_sT,
                                                      unsigned short* __restrict__ h) {
    int bx = blockIdx.x;
    int xcd = bx & 7, hi = bx >> 3;
    int i0 = (hi * 4 + (xcd & 3)) * 64;
    int n0 = (xcd >> 2) * 256;

    int tid = threadIdx.x;
    int w = tid >> 6, l = tid & 63, g = l >> 4, c = l & 15;
    int wm = w >> 3, wn = w & 7;      // main wave tile: rows wm*32, cols wn*32
    int gi = w & 3, gj = w >> 2;      // gen subtile: i-rows gi*16, j-rows gj*16

    const unsigned short* ap = bbn_h + (i0 + gi * 16 + c) * 64;
    short8 ga0 = ld8(ap), ga1 = ld8(ap + 32);
    float si = s[i0 + gi * 16 + c];

    __shared__ unsigned char Alds0[8192];
    __shared__ unsigned char Alds1[8192];

    f32x4 acc[2][2] = {};

    const unsigned short* gb = bbn_h + (gj * 16 + c) * 64;   // + j*64
    const float* sb = s + gj * 16 + g * 4;                   // + j
    const int wr_bo = ((gi * 16 + c) * 128 + (gj * 16 + g * 4) * 2) ^ ((c & 7) << 4);
    const unsigned short* bfr_base = cbn_sT + (size_t)(n0 + wn * 32 + c) * 8192 + g * 8;
    const int rd_row = wm * 32 + c;

    // prologue: gen tile 0 synchronously into Alds0
    {
        short8 b0 = ld8(gb), b1 = ld8(gb + 32);
        f32x4 sj4 = *reinterpret_cast<const f32x4*>(sb);
        f32x4 gf = {0.f, 0.f, 0.f, 0.f};
        gf = MFMA16(b0, ga0, gf);
        gf = MFMA16(b1, ga1, gf);
        unsigned short u[4];
        #pragma unroll
        for (int r = 0; r < 4; ++r) {
            float t = fmaf(2.f, gf[r], -(si + sj4[r]));
            float x = fmaxf(fmaf(fabsf(t), -0.015625f, 1.f), 0.f);
            u[r] = f2bf(exp2f(1.4f * log2f(x)));
        }
        *reinterpret_cast<uint2*>(&Alds0[wr_bo]) =
            make_uint2((unsigned)u[0] | ((unsigned)u[1] << 16),
                       (unsigned)u[2] | ((unsigned)u[3] << 16));
    }
    // issue gen loads for tile 1 (consumed at iter 0's gen-compute)
    short8 bA0 = ld8(gb + 64 * 64), bA1 = ld8(gb + 64 * 64 + 32);
    f32x4 sjA = *reinterpret_cast<const f32x4*>(sb + 64);
    short8 bB0, bB1; f32x4 sjB;
    __syncthreads();

#define SPEC_ITER(T, LR, LW, bc0, bc1, sjc, bn0, bn1, sjn) do {                    \
    const int j0_ = (T) << 6;                                                      \
    const int jn_ = ((T) + 2 < 128) ? (j0_ + 128) : 0;  /* clamp; garbage unused */\
    bn0 = ld8(gb + jn_ * 64);                                                      \
    bn1 = ld8(gb + jn_ * 64 + 32);                                                 \
    sjn = *reinterpret_cast<const f32x4*>(sb + jn_);                               \
    short8 bfr_[2][2];                                                             \
    _Pragma("unroll")                                                              \
    for (int kk = 0; kk < 2; ++kk)                                                 \
        _Pragma("unroll")                                                          \
        for (int nn = 0; nn < 2; ++nn)                                             \
            bfr_[kk][nn] = ld8(bfr_base + (size_t)nn * 16 * 8192 + j0_ + kk * 32); \
    short8 af_[2][2];                                                              \
    _Pragma("unroll")                                                              \
    for (int mi = 0; mi < 2; ++mi)                                                 \
        _Pragma("unroll")                                                          \
        for (int kk = 0; kk < 2; ++kk) {                                           \
            int bo_ = ((rd_row + mi * 16) * 128 + kk * 64 + g * 16) ^ ((c & 7) << 4); \
            af_[mi][kk] = *reinterpret_cast<const short8*>(&(LR)[bo_]);            \
        }                                                                          \
    if ((T) < 127) {  /* gen tile T+1 from regs loaded last iter */                \
        f32x4 gf_ = {0.f, 0.f, 0.f, 0.f};                                          \
        gf_ = MFMA16(bc0, ga0, gf_);                                               \
        gf_ = MFMA16(bc1, ga1, gf_);                                               \
        unsigned short u_[4];                                                      \
        _Pragma("unroll")                                                          \
        for (int r = 0; r < 4; ++r) {                                              \
            float t_ = fmaf(2.f, gf_[r], -(si + (sjc)[r]));                        \
            float x_ = fmaxf(fmaf(fabsf(t_), -0.015625f, 1.f), 0.f);               \
            u_[r] = f2bf(exp2f(1.4f * log2f(x_)));                                 \
        }                                                                          \
        *reinterpret_cast<uint2*>(&(LW)[wr_bo]) =                                  \
            make_uint2((unsigned)u_[0] | ((unsigned)u_[1] << 16),                  \
                       (unsigned)u_[2] | ((unsigned)u_[3] << 16));                 \
    }                                                                              \
    _Pragma("unroll")                                                              \
    for (int kk = 0; kk < 2; ++kk)                                                 \
        _Pragma("unroll")                                                          \
        for (int nn = 0; nn < 2; ++nn) {                                           \
            acc[0][nn] = MFMA16(af_[0][kk], bfr_[kk][nn], acc[0][nn]);             \
            acc[1][nn] = MFMA16(af_[1][kk], bfr_[kk][nn], acc[1][nn]);             \
        }                                                                          \
    __syncthreads();                                                               \
} while (0)

    for (int t2 = 0; t2 < 64; ++t2) {
        SPEC_ITER(2 * t2,     Alds0, Alds1, bA0, bA1, sjA, bB0, bB1, sjB);
        SPEC_ITER(2 * t2 + 1, Alds1, Alds0, bB0, bB1, sjB, bA0, bA1, sjA);
    }
#undef SPEC_ITER

    // epilogue: scale by dinv_i, store bf16 h
    #pragma unroll
    for (int mi = 0; mi < 2; ++mi) {
        f32x4 d4 = *reinterpret_cast<const f32x4*>(d + i0 + wm * 32 + mi * 16 + g * 4);
        #pragma unroll
        for (int r = 0; r < 4; ++r) {
            int row = i0 + wm * 32 + mi * 16 + g * 4 + r;
            float dinv = rsqrtf(d4[r]);
            #pragma unroll
            for (int nn = 0; nn < 2; ++nn)
                h[(size_t)row * 512 + n0 + wn * 32 + nn * 16 + c] = f2bf(acc[mi][nn][r] * dinv);
        }
    }
}

// ---- K4: out = sigmoid(h @ W + b), fp32 out ----------------------------------
// 512 blocks: 256 row-tiles (32 rows) x 2 col-tiles (256 cols); 8 waves 2x4
__global__ __launch_bounds__(512) void k_out(const unsigned short* __restrict__ h,
                                             const unsigned short* __restrict__ Wt,
                                             const float* __restrict__ b,
                                             float* __restrict__ out) {
    int bx = blockIdx.x;
    int i0 = (bx & 255) * 32, n0 = (bx >> 8) * 256;
    int tid = threadIdx.x;
    int w = tid >> 6, l = tid & 63, g = l >> 4, c = l & 15;
    int wm = w >> 2, wn = w & 3;   // rows wm*16, cols wn*64

    float bb[4];
    #pragma unroll
    for (int nn = 0; nn < 4; ++nn) bb[nn] = b[n0 + wn * 64 + nn * 16 + c];

    f32x4 acc[4] = {};
    for (int k0 = 0; k0 < 512; k0 += 64) {
        short8 af[2];
        #pragma unroll
        for (int kk = 0; kk < 2; ++kk)
            af[kk] = ld8(h + (size_t)(i0 + wm * 16 + c) * 512 + k0 + kk * 32 + g * 8);
        #pragma unroll
        for (int kk = 0; kk < 2; ++kk)
            #pragma unroll
            for (int nn = 0; nn < 4; ++nn) {
                short8 bf = ld8(Wt + (size_t)(n0 + wn * 64 + nn * 16 + c) * 512 + k0 + kk * 32 + g * 8);
                acc[nn] = MFMA16(af[kk], bf, acc[nn]);
            }
    }
    #pragma unroll
    for (int r = 0; r < 4; ++r) {
        int row = i0 + wm * 16 + g * 4 + r;
        #pragma unroll
        for (int nn = 0; nn < 4; ++nn) {
            float z = acc[nn][r] + bb[nn];
            out[(size_t)row * 512 + n0 + wn * 64 + nn * 16 + c] = 1.f / (1.f + exp2f(-1.44269504f * z));
        }
    }
}

extern "C" void kernel_launch(void* const* d_in, const int* in_sizes, int n_in,
                              void* d_out, int out_size, void* d_ws, size_t ws_size,
                              hipStream_t stream) {
    const float* bbn = (const float*)d_in[0];   // [8192, 64]
    const float* cbn = (const float*)d_in[1];   // [8192, 512]
    const float* W   = (const float*)d_in[2];   // [512, 512]
    const float* b   = (const float*)d_in[3];   // [512]
    float* out = (float*)d_out;                 // [8192, 512] fp32

    char* ws = (char*)d_ws;
    unsigned short* bbn_h  = (unsigned short*)(ws);                    // 1 MB
    float*          s      = (float*)(ws + (1u << 20));                // 32 KB
    float*          dd     = (float*)(ws + (1u << 20) + (1u << 15));   // 32 KB
    unsigned short* Wt     = (unsigned short*)(ws + (1u << 20) + (2u << 15));           // 512 KB
    unsigned short* cbn_sT = (unsigned short*)(ws + (1u << 20) + (2u << 15) + (1u << 19));        // 8 MB
    unsigned short* hbuf   = (unsigned short*)(ws + (1u << 20) + (2u << 15) + (1u << 19) + (1u << 23)); // 8 MB

    k_prep_bbn<<<2048, 256, 0, stream>>>(bbn, bbn_h, s);
    k_transpose_scale<<<64, 256, 0, stream>>>(W, Wt, nullptr, 512, 512);
    k_degree<<<512, 512, 0, stream>>>(bbn_h, s, dd);
    k_transpose_scale<<<1024, 256, 0, stream>>>(cbn, cbn_sT, dd, 8192, 512);
    k_spectral<<<256, 1024, 0, stream>>>(bbn_h, s, dd, cbn_sT, hbuf);
    k_out<<<512, 512, 0, stream>>>(hbuf, Wt, b, out);
}